// Round 1
// baseline (38375.821 us; speedup 1.0000x reference)
//
#include <hip/hip_runtime.h>
#include <math.h>

#define NPTS 2048
#define DIM  96
#define BS   1024   // threads in the sequential ward kernel

// Device-global state: rewritten in full every call (deterministic), so no
// reliance on d_ws size and no cross-call state hazards.
__device__ double g_xd[NPTS * DIM];
__device__ double g_sq[NPTS];
__device__ double g_d2[(size_t)NPTS * NPTS];   // 32 MB fp64 distance matrix
__device__ double g_rowmin[NPTS];
__device__ int    g_rowarg[NPTS];

// ---------------------------------------------------------------- prep ----
// Convert fp32 -> fp64, compute sq[r] = sum_d x[r][d]^2 (fp64).
__global__ void prep_kernel(const float* __restrict__ x) {
    int r = blockIdx.x;
    int t = threadIdx.x;
    __shared__ double s[DIM];
    if (t < DIM) {
        double v = (double)x[r * DIM + t];
        g_xd[r * DIM + t] = v;
        s[t] = v * v;
    }
    __syncthreads();
    if (t == 0) {
        double acc = 0.0;
        for (int d = 0; d < DIM; ++d) acc += s[d];
        g_sq[r] = acc;
    }
}

// ---------------------------------------------------------------- dist ----
// d2[r][c] = max(sq[r] + sq[c] - 2*dot(x_r, x_c), 0), diag = inf. fp64,
// same formula shape as the numpy reference.
__global__ void dist_kernel() {
    int c = blockIdx.x * blockDim.x + threadIdx.x;
    int r = blockIdx.y * blockDim.y + threadIdx.y;
    const double* __restrict__ xr = &g_xd[r * DIM];
    const double* __restrict__ xc = &g_xd[c * DIM];
    double acc = 0.0;
#pragma unroll 8
    for (int d = 0; d < DIM; ++d) acc += xr[d] * xc[d];
    double v = g_sq[r] + g_sq[c] - 2.0 * acc;
    if (v < 0.0) v = 0.0;
    if (r == c) v = (double)INFINITY;
    g_d2[(size_t)r * NPTS + c] = v;
}

// -------------------------------------------------------------- rowmin ----
// Per-row (min, argmin) over c != r with smallest-column tie-break, matching
// numpy's row-major flat argmin semantics.
__global__ void rowmin_kernel() {
    int r = blockIdx.x;
    int t = threadIdx.x;
    double bv = (double)INFINITY;
    int    bi = NPTS;
    const double* __restrict__ row = &g_d2[(size_t)r * NPTS];
    for (int c = t; c < NPTS; c += 256) {
        if (c == r) continue;
        double v = row[c];
        if (v < bv) { bv = v; bi = c; }   // ascending c + strict < keeps smallest col
    }
    for (int off = 32; off >= 1; off >>= 1) {
        double ov = __shfl_down(bv, off);
        int    oi = __shfl_down(bi, off);
        if (ov < bv || (ov == bv && oi < bi)) { bv = ov; bi = oi; }
    }
    __shared__ double sv[4];
    __shared__ int    si[4];
    int wid = t >> 6;
    if ((t & 63) == 0) { sv[wid] = bv; si[wid] = bi; }
    __syncthreads();
    if (t == 0) {
        for (int w = 1; w < 4; ++w)
            if (sv[w] < bv || (sv[w] == bv && si[w] < bi)) { bv = sv[w]; bi = si[w]; }
        g_rowmin[r] = bv;
        g_rowarg[r] = bi;
    }
}

// ---------------------------------------------------------------- ward ----
// Lexicographic (val, idx) block argmin: wave shuffle reduce, then cross-wave
// via LDS. 2 barriers total. All threads must call.
__device__ inline void block_argmin(double& bv, int& bi, double* s_redv,
                                    int* s_redi, int t) {
    for (int off = 32; off >= 1; off >>= 1) {
        double ov = __shfl_down(bv, off);
        int    oi = __shfl_down(bi, off);
        if (ov < bv || (ov == bv && oi < bi)) { bv = ov; bi = oi; }
    }
    int wid = t >> 6;
    if ((t & 63) == 0) { s_redv[wid] = bv; s_redi[wid] = bi; }
    __syncthreads();
    if (t < 64) {
        double v   = (t < BS / 64) ? s_redv[t] : (double)INFINITY;
        int    idx = (t < BS / 64) ? s_redi[t] : NPTS;
        for (int off = 32; off >= 1; off >>= 1) {
            double ov = __shfl_down(v, off);
            int    oi = __shfl_down(idx, off);
            if (ov < v || (ov == v && oi < idx)) { v = ov; idx = oi; }
        }
        if (t == 0) { s_redv[0] = v; s_redi[0] = idx; }
    }
    __syncthreads();
    bv = s_redv[0];
    bi = s_redi[0];
}

__global__ void __launch_bounds__(BS) ward_kernel(const int* __restrict__ kptr,
                                                  float* __restrict__ out) {
    __shared__ double        s_rowmin[NPTS];   // 16 KB
    __shared__ int           s_rowarg[NPTS];   //  8 KB
    __shared__ double        s_sizes[NPTS];    // 16 KB
    __shared__ unsigned char s_active[NPTS];   //  2 KB
    __shared__ int           s_cluster[NPTS];  //  8 KB
    __shared__ int           s_rescan[NPTS];   //  8 KB (also reused as label prefix)
    __shared__ int           s_nres;
    __shared__ double        s_redv[BS / 64];
    __shared__ int           s_redi[BS / 64];
    __shared__ int           s_i, s_j;
    __shared__ double        s_dij, s_si, s_sj;

    int t = threadIdx.x;
    int k = *kptr;

    for (int p = t; p < NPTS; p += BS) {
        s_rowmin[p]  = g_rowmin[p];
        s_rowarg[p]  = g_rowarg[p];
        s_sizes[p]   = 1.0;
        s_active[p]  = 1;
        s_cluster[p] = p;
    }
    __syncthreads();

    int nmerge = NPTS - k;
    for (int it = 0; it < nmerge; ++it) {
        // ---- 1. global argmin over active row minima (tie: smallest row) ----
        double bv = (double)INFINITY;
        int    bi = NPTS;
        for (int r = t; r < NPTS; r += BS) {
            double v = s_rowmin[r];           // inactive rows hold +inf
            if (v < bv) { bv = v; bi = r; }
        }
        block_argmin(bv, bi, s_redv, s_redi, t);
        if (t == 0) {
            int i = bi;
            int j = s_rowarg[i];              // guaranteed j > i (see analysis)
            s_i = i; s_j = j;
            s_dij = bv;
            s_si = s_sizes[i];
            s_sj = s_sizes[j];
            s_nres = 0;
        }
        __syncthreads();

        int    i   = s_i,   j  = s_j;
        double dij = s_dij, si = s_si, sj = s_sj;
        size_t rowi = (size_t)i * NPTS;
        size_t rowj = (size_t)j * NPTS;

        // ---- 2. Lance-Williams update + rowmin maintenance + cluster relabel ----
        for (int m = t; m < NPTS; m += BS) {
            if (s_cluster[m] == j) s_cluster[m] = i;
            if (s_active[m] && m != i && m != j) {
                double a  = g_d2[rowi + m];
                double b  = g_d2[rowj + m];
                double sm = s_sizes[m];
                double nd = ((si + sm) * a + (sj + sm) * b - sm * dij) / (si + sj + sm);
                g_d2[rowi + m]            = nd;
                g_d2[(size_t)m * NPTS + i] = nd;
                int am = s_rowarg[m];
                if (am == i || am == j) {
                    int slot = atomicAdd(&s_nres, 1);   // min location invalidated
                    s_rescan[slot] = m;
                } else if (nd < s_rowmin[m] || (nd == s_rowmin[m] && i < am)) {
                    s_rowmin[m] = nd;
                    s_rowarg[m] = i;
                }
            }
        }
        __syncthreads();
        if (t == 0) {
            s_sizes[i]  = si + sj;
            s_active[j] = 0;
            s_rowmin[j] = (double)INFINITY;
            int slot = atomicAdd(&s_nres, 1);           // row i always rescanned
            s_rescan[slot] = i;
        }
        __syncthreads();

        // ---- 3. full rescans for invalidated rows ----
        int nres = s_nres;
        for (int q = 0; q < nres; ++q) {
            int    r    = s_rescan[q];
            size_t rowr = (size_t)r * NPTS;
            double rv = (double)INFINITY;
            int    ri = NPTS;
            for (int c = t; c < NPTS; c += BS) {
                if (s_active[c] && c != r) {
                    double v = g_d2[rowr + c];
                    if (v < rv) { rv = v; ri = c; }
                }
            }
            block_argmin(rv, ri, s_redv, s_redi, t);
            if (t == 0) { s_rowmin[r] = rv; s_rowarg[r] = ri; }
            __syncthreads();
        }
    }

    // ---- labels: rank of surviving representative (sorted == first-occurrence
    // order, since each cluster's representative is its minimum point index) ----
    __syncthreads();
    if (t == 0) {
        int cnt = 0;
        for (int r = 0; r < NPTS; ++r) { s_rescan[r] = cnt; cnt += s_active[r]; }
    }
    __syncthreads();
    for (int p = t; p < NPTS; p += BS) {
        int lbl = s_rescan[s_cluster[p]];
        out[(size_t)p * k + lbl] = 1.0f;    // out pre-zeroed via hipMemsetAsync
    }
}

// -------------------------------------------------------------- launch ----
extern "C" void kernel_launch(void* const* d_in, const int* in_sizes, int n_in,
                              void* d_out, int out_size, void* d_ws, size_t ws_size,
                              hipStream_t stream) {
    const float* x    = (const float*)d_in[0];
    const int*   kptr = (const int*)d_in[1];
    float*       out  = (float*)d_out;

    hipMemsetAsync(d_out, 0, (size_t)out_size * sizeof(float), stream);

    prep_kernel<<<NPTS, 128, 0, stream>>>(x);
    dist_kernel<<<dim3(NPTS / 16, NPTS / 16), dim3(16, 16), 0, stream>>>();
    rowmin_kernel<<<NPTS, 256, 0, stream>>>();
    ward_kernel<<<1, BS, 0, stream>>>(kptr, out);
}